// Round 11
// baseline (277.640 us; speedup 1.0000x reference)
//
#include <hip/hip_runtime.h>

// Problem constants
#define BB 256
#define NN 5
#define EPSF 1e-8f
#define TPB 1024
#define FAN 8                 // members (blocks) per set, one 80-channel chunk each
#define NSETS 32              // concurrent b's
#define NIT 8                 // 256 / 32

typedef float f4 __attribute__((ext_vector_type(4)));

// One-read cooperative kernel v3. grid = 256 x 1024, 1 block/CU (all resident).
// Set members share bid%8 (same XCD under RR mapping -> L2-local sync; perf
// heuristic only). Member m owns channels [80m,80m+80) of all 5 shots of
// b = set + 32*it. Fan-in v3: parallel 16-lane post + wave fence + 1 counter
// bump; ONLY member 0 gathers (128 parallel lanes, one round trip), computes
// sim, publishes 5 floats + release flag; members spin relaxed on the flag.
__global__ __launch_bounds__(TPB, 4) void k_coop(const float* __restrict__ x,
                                                 float* __restrict__ out,
                                                 int* __restrict__ g_cnt,    // [BB*32] (128B/line)
                                                 int* __restrict__ g_rdy,    // [BB*32]
                                                 float* __restrict__ g_part, // [BB][FAN][16]
                                                 float* __restrict__ g_sim) {// [BB][16]
    __shared__ f4 xw[10000];            // 160,000 B: shot n at n*2000 f4
    __shared__ float feats_l[NN][100];  // member-local pooled dims
    __shared__ float red[2][16];        // wave partials
    __shared__ float gat[128];          // m0 gather buffer
    __shared__ float tot[16];
    __shared__ float s_sim[NN];

    const int tid = threadIdx.x;
    const int bid = blockIdx.x;
    const int xcd = bid & 7;
    const int j   = bid >> 3;
    const int k4  = j & 3;
    const int m   = j >> 2;             // member 0..7
    const int set = xcd + 8 * k4;       // 0..31

    const f4* __restrict__ xg = reinterpret_cast<const f4*>(x);

    // ---- prologue: prefetch chunk for it=0 into registers ----
    f4 rr[10];
    if (tid < 1000) {
        #pragma unroll
        for (int q = 0; q < 10; ++q) {
            const int sn = q >> 1, p = q & 1;
            rr[q] = xg[((size_t)(set * NN + sn)) * 16000 + m * 2000 + p * 1000 + tid];
        }
    }

    for (int it = 0; it < NIT; ++it) {
        const int b = set + NSETS * it;

        // ---- stage registers -> LDS ----
        if (tid < 1000) {
            #pragma unroll
            for (int q = 0; q < 10; ++q)
                xw[(q >> 1) * 2000 + (q & 1) * 1000 + tid] = rr[q];
        }
        __syncthreads();

        // ---- issue next chunk's loads now (complete during pool+sync) ----
        if (it + 1 < NIT && tid < 1000) {
            const int b2 = set + NSETS * (it + 1);
            #pragma unroll
            for (int q = 0; q < 10; ++q) {
                const int sn = q >> 1, p = q & 1;
                rr[q] = xg[((size_t)(b2 * NN + sn)) * 16000 + m * 2000 + p * 1000 + tid];
            }
        }

        // ---- pool: 500 threads, one (shot, local-d) cell each ----
        if (tid < 500) {
            const int sn = tid / 100;
            const int dl = tid - sn * 100;          // ocl*25 + oh*5 + ow
            const int ocl = dl / 25;
            const int r25 = dl - ocl * 25;
            const int oh  = r25 / 5;
            const int ow  = r25 - oh * 5;
            const float* __restrict__ xf = reinterpret_cast<const float*>(xw);
            const float* __restrict__ bp =
                xf + sn * 8000 + (ocl * 20) * 100 + oh * 20 + ow * 2;
            float s = 0.f;
            #pragma unroll
            for (int cc = 0; cc < 20; ++cc) {
                const float* q = bp + cc * 100;
                s += (q[0] + q[1]) + (q[10] + q[11]);
            }
            feats_l[sn][dl] = s * (1.f / 80.f);
        }
        __syncthreads();

        // ---- local partials over this member's 100 d-dims (waves 0,1) ----
        if (tid < 128) {
            float part[11];
            #pragma unroll
            for (int k = 0; k < 11; ++k) part[k] = 0.f;
            if (tid < 100) {
                float f[NN], p = 0.f;
                #pragma unroll
                for (int q = 0; q < NN; ++q) { f[q] = feats_l[q][tid]; p += f[q]; }
                #pragma unroll
                for (int q = 0; q < NN; ++q) { part[q] = f[q] * p; part[5 + q] = f[q] * f[q]; }
                part[10] = p * p;
            }
            #pragma unroll
            for (int off = 32; off >= 1; off >>= 1)
                #pragma unroll
                for (int k = 0; k < 11; ++k)
                    part[k] += __shfl_down(part[k], off, 64);
            if ((tid & 63) == 0) {
                #pragma unroll
                for (int k = 0; k < 11; ++k) red[tid >> 6][k] = part[k];
            }
        }
        __syncthreads();

        // ---- post: 16 parallel lane stores + wave fence + counter bump ----
        if (tid < 64) {
            if (tid < 16) {
                const float v = (tid < 11) ? red[0][tid] + red[1][tid] : 0.f;
                __hip_atomic_store(&g_part[((size_t)b * FAN + m) * 16 + tid], v,
                                   __ATOMIC_RELAXED, __HIP_MEMORY_SCOPE_AGENT);
            }
            __threadfence();   // wave-wide: drains the 16 stores, release cache-ops
            if (tid == 0)
                __hip_atomic_fetch_add(&g_cnt[(size_t)b * 32], 1,
                                       __ATOMIC_RELAXED, __HIP_MEMORY_SCOPE_AGENT);
        }

        if (m == 0) {
            // ---- member 0: spin relaxed, parallel gather, sim, publish ----
            if (tid == 0) {
                while (__hip_atomic_load(&g_cnt[(size_t)b * 32],
                                         __ATOMIC_RELAXED, __HIP_MEMORY_SCOPE_AGENT) < FAN)
                    __builtin_amdgcn_s_sleep(2);
            }
            __syncthreads();
            __threadfence();   // acquire side before reading partials
            if (tid < 128)
                gat[tid] = __hip_atomic_load(&g_part[(size_t)b * 128 + tid],
                                             __ATOMIC_RELAXED, __HIP_MEMORY_SCOPE_AGENT);
            __syncthreads();
            if (tid < 16) {
                float s = 0.f;
                #pragma unroll
                for (int mm = 0; mm < FAN; ++mm) s += gat[mm * 16 + tid];
                tot[tid] = s;
            }
            __syncthreads();
            if (tid == 0) {
                const float nb = sqrtf(tot[10]);
                #pragma unroll
                for (int q = 0; q < NN; ++q) {
                    const float sv = tot[q] / fmaxf(sqrtf(tot[5 + q]) * nb, EPSF);
                    s_sim[q] = sv;
                    __hip_atomic_store(&g_sim[(size_t)b * 16 + q], sv,
                                       __ATOMIC_RELAXED, __HIP_MEMORY_SCOPE_AGENT);
                }
                __threadfence();
                __hip_atomic_store(&g_rdy[(size_t)b * 32], 1,
                                   __ATOMIC_RELAXED, __HIP_MEMORY_SCOPE_AGENT);
            }
        } else {
            // ---- members 1..7: spin relaxed on ready flag, read 5 sims ----
            if (tid == 0) {
                while (__hip_atomic_load(&g_rdy[(size_t)b * 32],
                                         __ATOMIC_RELAXED, __HIP_MEMORY_SCOPE_AGENT) == 0)
                    __builtin_amdgcn_s_sleep(2);
                __threadfence();
                #pragma unroll
                for (int q = 0; q < NN; ++q)
                    s_sim[q] = __hip_atomic_load(&g_sim[(size_t)b * 16 + q],
                                                 __ATOMIC_RELAXED, __HIP_MEMORY_SCOPE_AGENT);
            }
        }
        __syncthreads();

        // ---- Phase C: out chunk from LDS, coalesced NT store ----
        if (tid < 1000) {
            const float w0 = s_sim[0], w1 = s_sim[1], w2 = s_sim[2],
                        w3 = s_sim[3], w4 = s_sim[4];
            f4* __restrict__ og = reinterpret_cast<f4*>(out) +
                                  (size_t)b * 16000 + m * 2000;
            #pragma unroll
            for (int h = 0; h < 2; ++h) {
                const int idx = h * 1000 + tid;
                f4 o = w0 * xw[idx]
                     + w1 * xw[2000 + idx]
                     + w2 * xw[4000 + idx]
                     + w3 * xw[6000 + idx]
                     + w4 * xw[8000 + idx];
                __builtin_nontemporal_store(o, og + idx);
            }
        }
        __syncthreads();   // xw consumed; next iteration overwrites
    }
}

extern "C" void kernel_launch(void* const* d_in, const int* in_sizes, int n_in,
                              void* d_out, int out_size, void* d_ws, size_t ws_size,
                              hipStream_t stream) {
    const float* x = (const float*)d_in[0];
    float* out = (float*)d_out;
    // ws layout: g_cnt [256*32 ints, 32KB] | g_rdy [32KB] | g_part [128KB] | g_sim [16KB]
    int*   g_cnt  = (int*)d_ws;
    int*   g_rdy  = (int*)((char*)d_ws + 32768);
    float* g_part = (float*)((char*)d_ws + 65536);
    float* g_sim  = (float*)((char*)d_ws + 65536 + 131072);
    hipMemsetAsync(d_ws, 0, 65536, stream);   // zero counters + flags only
    k_coop<<<BB, TPB, 0, stream>>>(x, out, g_cnt, g_rdy, g_part, g_sim);
}

// Round 12
// 135.806 us; speedup vs baseline: 2.0444x; 2.0444x over previous
//
#include <hip/hip_runtime.h>

// Problem constants
#define BB 256
#define NN 5
#define CHW 64000            // C*H*W floats per (b,n)
#define DD 800               // 32*5*5 pooled dims
#define EPSF 1e-8f
#define CB 128               // chunk of b: 128 * 1.28 MB = 164 MB < 256 MB L3

typedef float f4 __attribute__((ext_vector_type(4)));

// ---------------- Kernel A: pool one chunk of b ----------------
// CB*800 threads: one per (b,n,oc,oh) strip. Regular loads (allocate L3 —
// the residency out(c) will consume).
__global__ __launch_bounds__(256) void k_pool(const float* __restrict__ x,
                                              float* __restrict__ feats,
                                              int b0) {
    const int g = blockIdx.x * 256 + threadIdx.x;   // 0 .. CB*800-1
    const int b = b0 + g / 800;
    const int r = g - (g / 800) * 800;
    const int n = r / 160;
    const int q = r - n * 160;
    const int oc = q / 5;
    const int oh = q - oc * 5;
    const f4* __restrict__ p = reinterpret_cast<const f4*>(x) +
                               ((size_t)b * NN + n) * (CHW / 4) + oc * 500 + oh * 5;
    float s0 = 0.f, s1 = 0.f, s2 = 0.f, s3 = 0.f, s4 = 0.f;
    #pragma unroll 4
    for (int cc = 0; cc < 20; ++cc) {
        const f4 v0 = p[cc * 25 + 0];   // h0 w0..3
        const f4 v1 = p[cc * 25 + 1];   // h0 w4..7
        const f4 v2 = p[cc * 25 + 2];   // h0 w8,9 | h1 w0,1
        const f4 v3 = p[cc * 25 + 3];   // h1 w2..5
        const f4 v4 = p[cc * 25 + 4];   // h1 w6..9
        s0 += (v0.x + v0.y) + (v2.z + v2.w);
        s1 += (v0.z + v0.w) + (v3.x + v3.y);
        s2 += (v1.x + v1.y) + (v3.z + v3.w);
        s3 += (v1.z + v1.w) + (v4.x + v4.y);
        s4 += (v2.x + v2.y) + (v4.z + v4.w);
    }
    float* fp = feats + ((size_t)b * NN + n) * DD + oc * 25 + oh * 5;
    fp[0] = s0 * (1.f / 80.f);
    fp[1] = s1 * (1.f / 80.f);
    fp[2] = s2 * (1.f / 80.f);
    fp[3] = s3 * (1.f / 80.f);
    fp[4] = s4 * (1.f / 80.f);
}

// ---------------- Kernel B: cosine sims, one wave per b ----------------
__global__ __launch_bounds__(64) void k_sim(const float* __restrict__ feats,
                                            float* __restrict__ sim,
                                            int b0) {
    const int b = b0 + blockIdx.x;
    const int lane = threadIdx.x;
    const float* __restrict__ fb = feats + (size_t)b * NN * DD;
    float dot[NN] = {0.f, 0.f, 0.f, 0.f, 0.f};
    float na2[NN] = {0.f, 0.f, 0.f, 0.f, 0.f};
    float nb2 = 0.f;
    for (int d = lane; d < DD; d += 64) {
        float f[NN];
        float p = 0.f;
        #pragma unroll
        for (int n = 0; n < NN; ++n) { f[n] = fb[n * DD + d]; p += f[n]; }
        #pragma unroll
        for (int n = 0; n < NN; ++n) {
            dot[n] += f[n] * p;
            na2[n] += f[n] * f[n];
        }
        nb2 += p * p;
    }
    #pragma unroll
    for (int off = 32; off >= 1; off >>= 1) {
        #pragma unroll
        for (int n = 0; n < NN; ++n) {
            dot[n] += __shfl_down(dot[n], off, 64);
            na2[n] += __shfl_down(na2[n], off, 64);
        }
        nb2 += __shfl_down(nb2, off, 64);
    }
    if (lane == 0) {
        const float nb = sqrtf(nb2);
        #pragma unroll
        for (int n = 0; n < NN; ++n) {
            const float denom = fmaxf(sqrtf(na2[n]) * nb, EPSF);
            sim[b * NN + n] = dot[n] / denom;
        }
    }
}

// ---------------- Kernel C: weighted sum for one chunk of b ------------
// All reads are L3 hits (chunk was just streamed by k_pool and fits).
// Regular loads (hits must go through the cache); NT stores (no allocate).
__global__ __launch_bounds__(256) void k_out(const float* __restrict__ x,
                                             const float* __restrict__ sim,
                                             float* __restrict__ out,
                                             int b0) {
    const int i = blockIdx.x * 256 + threadIdx.x;   // 0 .. CB*16000-1
    const int b = b0 + i / 16000;                   // wave-uniform (16000%64==0)
    const int r = i - (i / 16000) * 16000;
    const f4* __restrict__ xp =
        reinterpret_cast<const f4*>(x) + (size_t)b * (NN * 16000) + r;
    const float s0 = sim[b * NN + 0];
    const float s1 = sim[b * NN + 1];
    const float s2 = sim[b * NN + 2];
    const float s3 = sim[b * NN + 3];
    const float s4 = sim[b * NN + 4];
    const f4 a0 = xp[0 * 16000];
    const f4 a1 = xp[1 * 16000];
    const f4 a2 = xp[2 * 16000];
    const f4 a3 = xp[3 * 16000];
    const f4 a4 = xp[4 * 16000];
    f4 o = s0 * a0 + s1 * a1 + s2 * a2 + s3 * a3 + s4 * a4;
    __builtin_nontemporal_store(
        o, reinterpret_cast<f4*>(out) + (size_t)b * 16000 + r);
}

extern "C" void kernel_launch(void* const* d_in, const int* in_sizes, int n_in,
                              void* d_out, int out_size, void* d_ws, size_t ws_size,
                              hipStream_t stream) {
    const float* x = (const float*)d_in[0];
    float* out = (float*)d_out;
    // workspace layout: feats [B*N*800] f32, then sim [B*N] f32
    float* feats = (float*)d_ws;
    float* sim = feats + (size_t)BB * NN * DD;

    for (int c = 0; c < BB / CB; ++c) {
        const int b0 = c * CB;
        k_pool<<<CB * 800 / 256, 256, 0, stream>>>(x, feats, b0);     // 400 blocks
        k_sim<<<CB, 64, 0, stream>>>(feats, sim, b0);
        k_out<<<CB * 16000 / 256, 256, 0, stream>>>(x, sim, out, b0); // 8000 blocks
    }
}

// Round 13
// 132.830 us; speedup vs baseline: 2.0902x; 1.0224x over previous
//
#include <hip/hip_runtime.h>

// Problem constants
#define BB 256
#define NN 5
#define CHW 64000            // C*H*W floats per (b,n)
#define DD 800               // 32*5*5 pooled dims
#define EPSF 1e-8f

typedef float f4 __attribute__((ext_vector_type(4)));

// ---------------- Kernel 1: pool + sim fused, one block per b ----------
// Threads 0..799 pool one (n,oc,oh) strip each (100 f4 loads, 400B-contiguous
// chunks) into LDS; then threads 0..799 each own one d-dim, compute the 11
// cosine partials, 16-wave shuffle+LDS reduce, thread 0 writes 5 sims.
// x is read once; only 5 floats written per b (no feats round-trip).
__global__ __launch_bounds__(1024, 4) void k_poolsim(const float* __restrict__ x,
                                                     float* __restrict__ sim) {
    __shared__ float fl[NN * DD];      // 16000 B: feats[n][d]
    __shared__ float red[17][11];
    const int tid = threadIdx.x;
    const int b = blockIdx.x;

    // ---- pool ----
    if (tid < NN * 160) {
        const int n  = tid / 160;
        const int r  = tid - n * 160;
        const int oc = r / 5;
        const int oh = r - oc * 5;
        const f4* __restrict__ p = reinterpret_cast<const f4*>(x) +
                                   ((size_t)b * NN + n) * (CHW / 4) + oc * 500 + oh * 5;
        float s0 = 0.f, s1 = 0.f, s2 = 0.f, s3 = 0.f, s4 = 0.f;
        #pragma unroll 4
        for (int cc = 0; cc < 20; ++cc) {
            const f4 v0 = p[cc * 25 + 0];   // h0 w0..3
            const f4 v1 = p[cc * 25 + 1];   // h0 w4..7
            const f4 v2 = p[cc * 25 + 2];   // h0 w8,9 | h1 w0,1
            const f4 v3 = p[cc * 25 + 3];   // h1 w2..5
            const f4 v4 = p[cc * 25 + 4];   // h1 w6..9
            s0 += (v0.x + v0.y) + (v2.z + v2.w);
            s1 += (v0.z + v0.w) + (v3.x + v3.y);
            s2 += (v1.x + v1.y) + (v3.z + v3.w);
            s3 += (v1.z + v1.w) + (v4.x + v4.y);
            s4 += (v2.x + v2.y) + (v4.z + v4.w);
        }
        float* fp = fl + n * DD + oc * 25 + oh * 5;
        fp[0] = s0 * (1.f / 80.f);
        fp[1] = s1 * (1.f / 80.f);
        fp[2] = s2 * (1.f / 80.f);
        fp[3] = s3 * (1.f / 80.f);
        fp[4] = s4 * (1.f / 80.f);
    }
    __syncthreads();

    // ---- 11 cosine partials, one d per thread ----
    float part[11];
    #pragma unroll
    for (int k = 0; k < 11; ++k) part[k] = 0.f;
    if (tid < DD) {
        float f[NN], p = 0.f;
        #pragma unroll
        for (int n = 0; n < NN; ++n) { f[n] = fl[n * DD + tid]; p += f[n]; }
        #pragma unroll
        for (int n = 0; n < NN; ++n) { part[n] = f[n] * p; part[5 + n] = f[n] * f[n]; }
        part[10] = p * p;
    }
    #pragma unroll
    for (int off = 32; off >= 1; off >>= 1)
        #pragma unroll
        for (int k = 0; k < 11; ++k)
            part[k] += __shfl_down(part[k], off, 64);
    const int wv = tid >> 6;
    if ((tid & 63) == 0) {
        #pragma unroll
        for (int k = 0; k < 11; ++k) red[wv][k] = part[k];
    }
    __syncthreads();
    if (tid < 11) {
        float s = 0.f;
        #pragma unroll
        for (int w = 0; w < 16; ++w) s += red[w][tid];
        red[16][tid] = s;
    }
    __syncthreads();
    if (tid == 0) {
        const float nb = sqrtf(red[16][10]);
        #pragma unroll
        for (int n = 0; n < NN; ++n) {
            const float denom = fmaxf(sqrtf(red[16][5 + n]) * nb, EPSF);
            sim[b * NN + n] = red[16][n] / denom;
        }
    }
}

// ---------------- Kernel 2: out[b] = sum_n sim[b,n] * x[b,n] -----------
// REVERSE b-order (early bids -> b=255, the L3-freshest slabs from K1's
// ascending stream) with regular loads; NT stores (write-once, no allocate).
__global__ __launch_bounds__(256) void k_out(const float* __restrict__ x,
                                             const float* __restrict__ sim,
                                             float* __restrict__ out) {
    const int i = blockIdx.x * 256 + threadIdx.x;   // 0 .. BB*16000-1
    const int b = (BB - 1) - i / 16000;             // descending b
    const int r = i - ((BB - 1) - b) * 16000;
    const f4* __restrict__ xp =
        reinterpret_cast<const f4*>(x) + (size_t)b * (NN * 16000) + r;
    const float s0 = sim[b * NN + 0];
    const float s1 = sim[b * NN + 1];
    const float s2 = sim[b * NN + 2];
    const float s3 = sim[b * NN + 3];
    const float s4 = sim[b * NN + 4];
    const f4 a0 = xp[0 * 16000];
    const f4 a1 = xp[1 * 16000];
    const f4 a2 = xp[2 * 16000];
    const f4 a3 = xp[3 * 16000];
    const f4 a4 = xp[4 * 16000];
    f4 o = s0 * a0 + s1 * a1 + s2 * a2 + s3 * a3 + s4 * a4;
    __builtin_nontemporal_store(
        o, reinterpret_cast<f4*>(out) + (size_t)b * 16000 + r);
}

extern "C" void kernel_launch(void* const* d_in, const int* in_sizes, int n_in,
                              void* d_out, int out_size, void* d_ws, size_t ws_size,
                              hipStream_t stream) {
    const float* x = (const float*)d_in[0];
    float* out = (float*)d_out;
    float* sim = (float*)d_ws;   // [B*N] f32

    k_poolsim<<<BB, 1024, 0, stream>>>(x, sim);                   // 256 blocks
    k_out<<<BB * 16000 / 256, 256, 0, stream>>>(x, sim, out);     // 16000 blocks
}